// Round 1
// baseline (1307.049 us; speedup 1.0000x reference)
//
#include <hip/hip_runtime.h>
#include <math.h>

// SysMaxOfAtoms: segment max over sorted mol_index.
// features: [N_ATOMS, 256] fp32; mol_index: [N_ATOMS] int32 sorted; out: [N_MOL, 256] fp32.
// Memory-bound: 1.024 GB feature read -> ~165 us roofline at 6.3 TB/s.

constexpr int FEAT = 256;      // feature dim (lane l owns floats [4l,4l+4))
constexpr int CHUNK = 128;     // atoms per one-wave block
constexpr unsigned ENC_NEG_INF = 0x007FFFFFu;  // enc(-inf)

// Order-preserving f32 -> u32 map: max over uint == max over float.
__device__ __forceinline__ unsigned enc_f32(float f) {
    unsigned u = __float_as_uint(f);
    return (u & 0x80000000u) ? ~u : (u | 0x80000000u);
}
__device__ __forceinline__ float dec_f32(unsigned e) {
    unsigned u = (e & 0x80000000u) ? (e ^ 0x80000000u) : ~e;
    return __uint_as_float(u);
}

__global__ void init_kernel(unsigned* __restrict__ out, int n) {
    int stride = gridDim.x * blockDim.x;
    for (int i = blockIdx.x * blockDim.x + threadIdx.x; i < n; i += stride)
        out[i] = ENC_NEG_INF;
}

__global__ __launch_bounds__(64) void segmax_kernel(
        const float4* __restrict__ feats,
        const int* __restrict__ mol,
        unsigned* __restrict__ out,
        int n_atoms) {
    __shared__ int smol[CHUNK + 1];
    const int lane = threadIdx.x;           // 0..63, owns features [4*lane, 4*lane+4)
    const int base = blockIdx.x * CHUNK;
    const int end = min(base + CHUNK, n_atoms);

    // Stage this chunk's mol ids (plus one lookahead) in LDS.
    for (int i = lane; i <= CHUNK; i += 64) {
        int a = base + i;
        smol[i] = (a < n_atoms) ? mol[a] : -1;
    }
    __syncthreads();

    float4 m = make_float4(-INFINITY, -INFINITY, -INFINITY, -INFINITY);
    for (int a = base; a < end; ++a) {
        // Coalesced 1 KiB row read: 64 lanes x float4.
        float4 f = feats[(size_t)a * (FEAT / 4) + lane];
        m.x = fmaxf(m.x, f.x);
        m.y = fmaxf(m.y, f.y);
        m.z = fmaxf(m.z, f.z);
        m.w = fmaxf(m.w, f.w);
        int li = a - base;
        int cur = smol[li];
        // Flush running max when the segment ends or the chunk ends.
        if (cur != smol[li + 1] || a == end - 1) {
            unsigned* o = out + (size_t)cur * FEAT + lane * 4;
            atomicMax(o + 0, enc_f32(m.x));
            atomicMax(o + 1, enc_f32(m.y));
            atomicMax(o + 2, enc_f32(m.z));
            atomicMax(o + 3, enc_f32(m.w));
            m = make_float4(-INFINITY, -INFINITY, -INFINITY, -INFINITY);
        }
    }
}

__global__ void finalize_kernel(unsigned* __restrict__ out, int n) {
    int stride = gridDim.x * blockDim.x;
    for (int i = blockIdx.x * blockDim.x + threadIdx.x; i < n; i += stride) {
        unsigned e = out[i];
        float f = (e == ENC_NEG_INF) ? 0.0f : dec_f32(e);  // empty segment -> 0 (matches ref)
        out[i] = __float_as_uint(f);
    }
}

extern "C" void kernel_launch(void* const* d_in, const int* in_sizes, int n_in,
                              void* d_out, int out_size, void* d_ws, size_t ws_size,
                              hipStream_t stream) {
    const float4* feats = (const float4*)d_in[0];
    const int* mol = (const int*)d_in[1];
    const int n_atoms = in_sizes[1];          // features count / FEAT
    unsigned* out_u = (unsigned*)d_out;       // encoded in place, decoded by finalize

    init_kernel<<<2048, 256, 0, stream>>>(out_u, out_size);

    const int n_blocks = (n_atoms + CHUNK - 1) / CHUNK;
    segmax_kernel<<<n_blocks, 64, 0, stream>>>(feats, mol, out_u, n_atoms);

    finalize_kernel<<<2048, 256, 0, stream>>>(out_u, out_size);
}